// Round 1
// baseline (576.073 us; speedup 1.0000x reference)
//
#include <hip/hip_runtime.h>
#include <hip/hip_bf16.h>

#define B_  256
#define T_  256
#define C_  384
#define HS_ 64
#define BT_ (B_*T_)

// ---------- helpers ----------
__device__ __forceinline__ float bf2f(unsigned short v) {
    return __uint_as_float(((unsigned)v) << 16);
}
__device__ __forceinline__ unsigned short f2bf(float f) {
    unsigned u = __float_as_uint(f);
    u += 0x7FFFu + ((u >> 16) & 1u);   // round-to-nearest-even
    return (unsigned short)(u >> 16);
}
__device__ __forceinline__ void fma4(float4& a, float s, const float4& w) {
    a.x = fmaf(s, w.x, a.x);
    a.y = fmaf(s, w.y, a.y);
    a.z = fmaf(s, w.z, a.z);
    a.w = fmaf(s, w.w, a.w);
}
__device__ __forceinline__ void store4(unsigned short* p, const float4& v) {
    ushort4 u;
    u.x = f2bf(v.x); u.y = f2bf(v.y); u.z = f2bf(v.z); u.w = f2bf(v.w);
    *(ushort4*)p = u;
}

// ---------- kernel 1: fused QKV projection (fp32 compute, bf16 store) ----------
// Grid: BT_/32 blocks x 256 threads. Each block: 32 rows x 192 cols.
// X tile staged in LDS (row stride 388 to avoid 384-stride bank conflicts),
// W streamed from global (L2-resident, ~600 MB total L2 traffic).
__global__ __launch_bounds__(256) void qkv_proj(
    const float* __restrict__ X,
    const float* __restrict__ Wq,
    const float* __restrict__ Wk,
    const float* __restrict__ Wv,
    unsigned short* __restrict__ Qo,
    unsigned short* __restrict__ Ko,
    unsigned short* __restrict__ Vo)
{
    __shared__ float Xs[32][388];   // 388 % 32 = 4 -> rows land on distinct banks
    const int t    = threadIdx.x;
    const int row0 = blockIdx.x * 32;

    // cooperative coalesced load of the 32x384 X tile
    const float4* Xv = (const float4*)(X + (size_t)row0 * C_);
    for (int i = t; i < 32 * (C_/4); i += 256) {
        int r  = i / (C_/4);
        int c4 = i - r * (C_/4);
        *(float4*)&Xs[r][c4*4] = Xv[i];
    }
    __syncthreads();

    const int tx = t & 15;        // column group: cols tx*4..tx*4+3 of each of Q/K/V
    const int ty = t >> 4;        // row group: rows ty*2, ty*2+1
    const int r0 = ty*2, r1 = r0 + 1;

    const float4 z = make_float4(0.f, 0.f, 0.f, 0.f);
    float4 aq0=z, aq1=z, ak0=z, ak1=z, av0=z, av1=z;
    const float4* wq4 = (const float4*)Wq + tx;   // [k*16] strides over k
    const float4* wk4 = (const float4*)Wk + tx;
    const float4* wv4 = (const float4*)Wv + tx;

    #pragma unroll 4
    for (int k = 0; k < C_; ++k) {
        float x0 = Xs[r0][k];
        float x1 = Xs[r1][k];
        float4 wq = wq4[k*16];
        float4 wk = wk4[k*16];
        float4 wv = wv4[k*16];
        fma4(aq0, x0, wq); fma4(aq1, x1, wq);
        fma4(ak0, x0, wk); fma4(ak1, x1, wk);
        fma4(av0, x0, wv); fma4(av1, x1, wv);
    }

    const size_t o0 = (size_t)(row0 + r0) * HS_ + tx*4;
    const size_t o1 = (size_t)(row0 + r1) * HS_ + tx*4;
    store4(Qo + o0, aq0); store4(Qo + o1, aq1);
    store4(Ko + o0, ak0); store4(Ko + o1, ak1);
    store4(Vo + o0, av0); store4(Vo + o1, av1);
}

// ---------- kernel 2: causal attention, one block per (batch, q-row) ----------
__global__ __launch_bounds__(256) void attn(
    const unsigned short* __restrict__ Q,
    const unsigned short* __restrict__ K,
    const unsigned short* __restrict__ V,
    float* __restrict__ out)
{
    const int gb   = blockIdx.x;        // b*T + qpos  (consecutive blocks share batch -> L2 locality)
    const int b    = gb >> 8;
    const int qpos = gb & 255;
    const int t    = threadIdx.x;

    __shared__ float qrow[HS_];
    __shared__ float w_sh[T_];
    __shared__ float red[4];
    __shared__ float partial[4][HS_];

    if (t < HS_) qrow[t] = bf2f(Q[(size_t)gb * HS_ + t]);
    __syncthreads();

    const float scale = 0.05103103630798288f;   // 384^-0.5 (reference scales by C, not HS)

    // phase 1: scores (thread t owns key position t)
    float s = -3.402823466e38f;
    if (t <= qpos) {
        const uint4* krow = (const uint4*)(K + ((size_t)(b * T_) + t) * HS_);
        float acc = 0.f;
        #pragma unroll
        for (int i = 0; i < 8; ++i) {
            uint4 u = krow[i];
            unsigned vals[4] = {u.x, u.y, u.z, u.w};
            #pragma unroll
            for (int j = 0; j < 4; ++j) {
                acc = fmaf(bf2f((unsigned short)(vals[j] & 0xFFFFu)), qrow[i*8 + j*2],     acc);
                acc = fmaf(bf2f((unsigned short)(vals[j] >> 16)),     qrow[i*8 + j*2 + 1], acc);
            }
        }
        s = acc * scale;
    }

    // phase 2: block-wide softmax (max, then sum)
    float m = s;
    #pragma unroll
    for (int off = 32; off > 0; off >>= 1)
        m = fmaxf(m, __shfl_xor(m, off));
    if ((t & 63) == 0) red[t >> 6] = m;
    __syncthreads();
    const float M = fmaxf(fmaxf(red[0], red[1]), fmaxf(red[2], red[3]));
    const float p = (t <= qpos) ? __expf(s - M) : 0.f;
    float sm = p;
    #pragma unroll
    for (int off = 32; off > 0; off >>= 1)
        sm += __shfl_xor(sm, off);
    __syncthreads();                     // everyone done reading red (M)
    if ((t & 63) == 0) red[t >> 6] = sm;
    __syncthreads();
    const float S = red[0] + red[1] + red[2] + red[3];
    w_sh[t] = p / S;
    __syncthreads();

    // phase 3: out[h] = sum_k w[k] * V[b][k][h]; 4 partials per channel
    const int h    = t & 63;
    const int part = t >> 6;             // wave-uniform
    const int k0   = part * 64;
    float acc = 0.f;
    if (k0 <= qpos) {
        const unsigned short* vp = V + ((size_t)(b * T_) + k0) * HS_ + h;
        const int kend = min(64, qpos - k0 + 1);   // wave-uniform bound
        for (int kk = 0; kk < kend; ++kk)
            acc = fmaf(w_sh[k0 + kk], bf2f(vp[(size_t)kk * HS_]), acc);
    }
    partial[part][h] = acc;
    __syncthreads();
    if (t < HS_)
        out[(size_t)gb * HS_ + t] = partial[0][t] + partial[1][t] + partial[2][t] + partial[3][t];
}

// ---------- launch ----------
extern "C" void kernel_launch(void* const* d_in, const int* in_sizes, int n_in,
                              void* d_out, int out_size, void* d_ws, size_t ws_size,
                              hipStream_t stream) {
    const float* X  = (const float*)d_in[0];
    const float* Wq = (const float*)d_in[1];
    const float* Wk = (const float*)d_in[2];
    const float* Wv = (const float*)d_in[3];
    float* out = (float*)d_out;

    unsigned short* Q = (unsigned short*)d_ws;                  // 3 * 65536*64 bf16 = 24 MB
    unsigned short* K = Q + (size_t)BT_ * HS_;
    unsigned short* V = K + (size_t)BT_ * HS_;

    qkv_proj<<<BT_/32, 256, 0, stream>>>(X, Wq, Wk, Wv, Q, K, V);
    attn<<<BT_, 256, 0, stream>>>(Q, K, V, out);
}

// Round 2
// 277.244 us; speedup vs baseline: 2.0779x; 2.0779x over previous
//
#include <hip/hip_runtime.h>
#include <hip/hip_bf16.h>

#define B_  256
#define T_  256
#define C_  384
#define HS_ 64
#define BT_ (B_*T_)

typedef __attribute__((ext_vector_type(8))) short short8;
typedef __attribute__((ext_vector_type(4))) float f32x4;

// ---------- helpers ----------
__device__ __forceinline__ float bf2f(unsigned short v) {
    return __uint_as_float(((unsigned)v) << 16);
}
__device__ __forceinline__ unsigned short f2bf(float f) {
    unsigned u = __float_as_uint(f);
    u += 0x7FFFu + ((u >> 16) & 1u);   // round-to-nearest-even
    return (unsigned short)(u >> 16);
}

// ---------- kernel 0: W -> Wt[192][384] bf16 (transposed, Q|K|V stacked) ----------
__global__ __launch_bounds__(256) void prep_w(
    const float* __restrict__ Wq, const float* __restrict__ Wk,
    const float* __restrict__ Wv, unsigned short* __restrict__ Wt)
{
    int i = blockIdx.x * 256 + threadIdx.x;     // 192*384 = 73728 exactly
    int n = i / C_, k = i - n * C_;
    const float* src = (n < 64) ? Wq : (n < 128) ? Wk : Wv;
    Wt[i] = f2bf(src[(size_t)k * HS_ + (n & 63)]);
}

// ---------- kernel 1: QKV projection via bf16 MFMA ----------
// Block: 256 thr = 4 waves, tile M=64 x N=192, K-step 32, double-buffered LDS.
// Wave w owns cols [w*48, w*48+48): 3 B-frags x 4 A-frags = 12 MFMA/step.
// Layouts (16x16x32): A: row=l&15, k=(l>>4)*8+j ; B: col=l&15, k=(l>>4)*8+j ;
//                     D: col=l&15, row=(l>>4)*4+reg  [guide m89]
#define LDK 40   // 32 k-elems + 8 pad (row stride 80 B -> conflict-free b128)
__global__ __launch_bounds__(256) void qkv_mfma(
    const float* __restrict__ X, const unsigned short* __restrict__ Wt,
    unsigned short* __restrict__ Qo, unsigned short* __restrict__ Ko,
    unsigned short* __restrict__ Vo)
{
    __shared__ unsigned short Xs[2][64 * LDK];    // 10240 B
    __shared__ unsigned short Ws[2][192 * LDK];   // 30720 B
    const int t    = threadIdx.x;
    const int lane = t & 63;
    const int w    = t >> 6;
    const int lo4  = lane & 15;
    const int hi4  = lane >> 4;
    const int row0 = blockIdx.x * 64;

    auto stageX = [&](int buf, int k0) {          // 64 rows x 32 k, 1 chunk/thread
        int r = t >> 2, k8 = (t & 3) * 8;
        const float4* g = (const float4*)(X + (size_t)(row0 + r) * C_ + k0 + k8);
        float4 a = g[0], b = g[1];
        ushort4 lo = { f2bf(a.x), f2bf(a.y), f2bf(a.z), f2bf(a.w) };
        ushort4 hi = { f2bf(b.x), f2bf(b.y), f2bf(b.z), f2bf(b.w) };
        *(ushort4*)&Xs[buf][r * LDK + k8]     = lo;
        *(ushort4*)&Xs[buf][r * LDK + k8 + 4] = hi;
    };
    auto stageW = [&](int buf, int k0) {          // 192 rows x 32 k, 3 chunks/thread
        #pragma unroll
        for (int i = 0; i < 3; ++i) {
            int c = t + i * 256;
            int n = c >> 2, k8 = (c & 3) * 8;
            uint4 d = *(const uint4*)(Wt + (size_t)n * C_ + k0 + k8);
            *(uint4*)&Ws[buf][n * LDK + k8] = d;
        }
    };

    stageX(0, 0);
    stageW(0, 0);
    __syncthreads();

    f32x4 acc[4][3];
    #pragma unroll
    for (int m = 0; m < 4; ++m)
        #pragma unroll
        for (int f = 0; f < 3; ++f)
            acc[m][f] = (f32x4){0.f, 0.f, 0.f, 0.f};

    const int kofs = hi4 * 8;
    #pragma unroll 1
    for (int s = 0; s < 12; ++s) {
        const int cur = s & 1;
        if (s < 11) { stageX(cur ^ 1, (s + 1) * 32); stageW(cur ^ 1, (s + 1) * 32); }

        short8 af[4], bf[3];
        #pragma unroll
        for (int m = 0; m < 4; ++m)
            af[m] = *(const short8*)&Xs[cur][(m * 16 + lo4) * LDK + kofs];
        #pragma unroll
        for (int f = 0; f < 3; ++f)
            bf[f] = *(const short8*)&Ws[cur][(w * 48 + f * 16 + lo4) * LDK + kofs];
        #pragma unroll
        for (int m = 0; m < 4; ++m)
            #pragma unroll
            for (int f = 0; f < 3; ++f)
                acc[m][f] = __builtin_amdgcn_mfma_f32_16x16x32_bf16(af[m], bf[f], acc[m][f], 0, 0, 0);
        __syncthreads();
    }

    // epilogue: D col = w*48 + f*16 + lo4 ; rows = row0 + m*16 + hi4*4 + r
    #pragma unroll
    for (int m = 0; m < 4; ++m) {
        #pragma unroll
        for (int f = 0; f < 3; ++f) {
            int n = w * 48 + f * 16 + lo4;
            unsigned short* dst = (n < 64) ? Qo : (n < 128) ? Ko : Vo;
            int h = n & 63;
            #pragma unroll
            for (int r = 0; r < 4; ++r) {
                int row = row0 + m * 16 + hi4 * 4 + r;
                dst[(size_t)row * HS_ + h] = f2bf(acc[m][f][r]);
            }
        }
    }
}

// ---------- kernel 2: causal attention, one block per (batch, q-row) ----------
__global__ __launch_bounds__(256) void attn(
    const unsigned short* __restrict__ Q,
    const unsigned short* __restrict__ K,
    const unsigned short* __restrict__ V,
    float* __restrict__ out)
{
    const int gb   = blockIdx.x;
    const int b    = gb >> 8;
    const int qpos = gb & 255;
    const int t    = threadIdx.x;

    __shared__ float qrow[HS_];
    __shared__ float w_sh[T_];
    __shared__ float red[4];
    __shared__ float partial[4][HS_];

    if (t < HS_) qrow[t] = bf2f(Q[(size_t)gb * HS_ + t]);
    __syncthreads();

    const float scale = 0.05103103630798288f;   // 384^-0.5

    // phase 1: scores (thread t owns key position t)
    float s = -3.402823466e38f;
    if (t <= qpos) {
        const uint4* krow = (const uint4*)(K + ((size_t)(b * T_) + t) * HS_);
        float acc = 0.f;
        #pragma unroll
        for (int i = 0; i < 8; ++i) {
            uint4 u = krow[i];
            unsigned vals[4] = {u.x, u.y, u.z, u.w};
            #pragma unroll
            for (int j = 0; j < 4; ++j) {
                acc = fmaf(bf2f((unsigned short)(vals[j] & 0xFFFFu)), qrow[i*8 + j*2],     acc);
                acc = fmaf(bf2f((unsigned short)(vals[j] >> 16)),     qrow[i*8 + j*2 + 1], acc);
            }
        }
        s = acc * scale;
    }

    // phase 2: block-wide softmax
    float m = s;
    #pragma unroll
    for (int off = 32; off > 0; off >>= 1)
        m = fmaxf(m, __shfl_xor(m, off));
    if ((t & 63) == 0) red[t >> 6] = m;
    __syncthreads();
    const float M = fmaxf(fmaxf(red[0], red[1]), fmaxf(red[2], red[3]));
    const float p = (t <= qpos) ? __expf(s - M) : 0.f;
    float sm = p;
    #pragma unroll
    for (int off = 32; off > 0; off >>= 1)
        sm += __shfl_xor(sm, off);
    __syncthreads();
    if ((t & 63) == 0) red[t >> 6] = sm;
    __syncthreads();
    const float S = red[0] + red[1] + red[2] + red[3];
    w_sh[t] = p / S;            // zero beyond qpos -> phase 3 can run constant bounds
    __syncthreads();

    // phase 3: out[h] = sum_k w[k]*V[b][k][h]; constant-64 unrolled loop per part
    const int h    = t & 63;
    const int part = t >> 6;
    const int k0   = part * 64;
    float acc = 0.f;
    if (k0 <= qpos) {
        const unsigned short* vp = V + ((size_t)(b * T_) + k0) * HS_ + h;
        #pragma unroll 16
        for (int kk = 0; kk < 64; ++kk)
            acc = fmaf(w_sh[k0 + kk], bf2f(vp[(size_t)kk * HS_]), acc);
    }
    partial[part][h] = acc;
    __syncthreads();
    if (t < HS_)
        out[(size_t)gb * HS_ + t] = partial[0][t] + partial[1][t] + partial[2][t] + partial[3][t];
}

// ---------- launch ----------
extern "C" void kernel_launch(void* const* d_in, const int* in_sizes, int n_in,
                              void* d_out, int out_size, void* d_ws, size_t ws_size,
                              hipStream_t stream) {
    const float* X  = (const float*)d_in[0];
    const float* Wq = (const float*)d_in[1];
    const float* Wk = (const float*)d_in[2];
    const float* Wv = (const float*)d_in[3];
    float* out = (float*)d_out;

    unsigned short* Q  = (unsigned short*)d_ws;                 // 3 x 8 MB bf16
    unsigned short* K  = Q + (size_t)BT_ * HS_;
    unsigned short* V  = K + (size_t)BT_ * HS_;
    unsigned short* Wt = V + (size_t)BT_ * HS_;                 // 192*384 bf16

    prep_w<<<(192 * C_) / 256, 256, 0, stream>>>(Wq, Wk, Wv, Wt);
    qkv_mfma<<<BT_ / 64, 256, 0, stream>>>(X, Wt, Q, K, V);
    attn<<<BT_, 256, 0, stream>>>(Q, K, V, out);
}

// Round 3
// 59.541 us; speedup vs baseline: 9.6752x; 4.6563x over previous
//
#include <hip/hip_runtime.h>
#include <hip/hip_bf16.h>

#define B_  256
#define T_  256
#define C_  384
#define HS_ 64
#define BT_ (B_*T_)

typedef __attribute__((ext_vector_type(8))) short short8;
typedef __attribute__((ext_vector_type(4))) float f32x4;

// ---------- helpers ----------
__device__ __forceinline__ float bf2f(unsigned short v) {
    return __uint_as_float(((unsigned)v) << 16);
}
__device__ __forceinline__ unsigned short f2bf(float f) {
    unsigned u = __float_as_uint(f);
    u += 0x7FFFu + ((u >> 16) & 1u);   // round-to-nearest-even
    return (unsigned short)(u >> 16);
}

// ---------- kernel 0: W -> Wt[192][384] bf16 (transposed, Q|K|V stacked) ----------
// Q columns pre-scaled by 384^-0.5 (reference scales scores by C^-0.5).
__global__ __launch_bounds__(256) void prep_w(
    const float* __restrict__ Wq, const float* __restrict__ Wk,
    const float* __restrict__ Wv, unsigned short* __restrict__ Wt)
{
    int i = blockIdx.x * 256 + threadIdx.x;     // 192*384 = 73728 exactly
    int n = i / C_, k = i - n * C_;
    const float* src = (n < 64) ? Wq : (n < 128) ? Wk : Wv;
    float v = src[(size_t)k * HS_ + (n & 63)];
    if (n < 64) v *= 0.05103103630798288f;
    Wt[i] = f2bf(v);
}

// ---------- kernel 1: QKV projection via bf16 MFMA ----------
// Block: 256 thr = 4 waves, tile M=64 x N=192, K-step 32, double-buffered LDS.
// Layouts (16x16x32): A: row=l&15, k=(l>>4)*8+j ; B: col=l&15, k=(l>>4)*8+j ;
//                     D: col=l&15, row=(l>>4)*4+reg
#define LDK 40
__global__ __launch_bounds__(256) void qkv_mfma(
    const float* __restrict__ X, const unsigned short* __restrict__ Wt,
    unsigned short* __restrict__ Qo, unsigned short* __restrict__ Ko,
    unsigned short* __restrict__ Vto)
{
    __shared__ unsigned short Xs[2][64 * LDK];
    __shared__ unsigned short Ws[2][192 * LDK];
    const int t    = threadIdx.x;
    const int lane = t & 63;
    const int w    = t >> 6;
    const int lo4  = lane & 15;
    const int hi4  = lane >> 4;
    const int row0 = blockIdx.x * 64;

    auto stageX = [&](int buf, int k0) {
        int r = t >> 2, k8 = (t & 3) * 8;
        const float4* g = (const float4*)(X + (size_t)(row0 + r) * C_ + k0 + k8);
        float4 a = g[0], b = g[1];
        ushort4 lo = { f2bf(a.x), f2bf(a.y), f2bf(a.z), f2bf(a.w) };
        ushort4 hi = { f2bf(b.x), f2bf(b.y), f2bf(b.z), f2bf(b.w) };
        *(ushort4*)&Xs[buf][r * LDK + k8]     = lo;
        *(ushort4*)&Xs[buf][r * LDK + k8 + 4] = hi;
    };
    auto stageW = [&](int buf, int k0) {
        #pragma unroll
        for (int i = 0; i < 3; ++i) {
            int c = t + i * 256;
            int n = c >> 2, k8 = (c & 3) * 8;
            uint4 d = *(const uint4*)(Wt + (size_t)n * C_ + k0 + k8);
            *(uint4*)&Ws[buf][n * LDK + k8] = d;
        }
    };

    stageX(0, 0);
    stageW(0, 0);
    __syncthreads();

    f32x4 acc[4][3];
    #pragma unroll
    for (int m = 0; m < 4; ++m)
        #pragma unroll
        for (int f = 0; f < 3; ++f)
            acc[m][f] = (f32x4){0.f, 0.f, 0.f, 0.f};

    const int kofs = hi4 * 8;
    #pragma unroll 1
    for (int s = 0; s < 12; ++s) {
        const int cur = s & 1;
        if (s < 11) { stageX(cur ^ 1, (s + 1) * 32); stageW(cur ^ 1, (s + 1) * 32); }

        short8 af[4], bf[3];
        #pragma unroll
        for (int m = 0; m < 4; ++m)
            af[m] = *(const short8*)&Xs[cur][(m * 16 + lo4) * LDK + kofs];
        #pragma unroll
        for (int f = 0; f < 3; ++f)
            bf[f] = *(const short8*)&Ws[cur][(w * 48 + f * 16 + lo4) * LDK + kofs];
        #pragma unroll
        for (int m = 0; m < 4; ++m)
            #pragma unroll
            for (int f = 0; f < 3; ++f)
                acc[m][f] = __builtin_amdgcn_mfma_f32_16x16x32_bf16(af[m], bf[f], acc[m][f], 0, 0, 0);
        __syncthreads();
    }

    // epilogue: col n = w*48+f*16+lo4 ; row = row0 + m*16 + hi4*4 + r
    // Q,K natural [tok][64]; V transposed -> Vt[b*64+h][tok&255]
    #pragma unroll
    for (int m = 0; m < 4; ++m) {
        #pragma unroll
        for (int f = 0; f < 3; ++f) {
            int n = w * 48 + f * 16 + lo4;
            #pragma unroll
            for (int r = 0; r < 4; ++r) {
                int row = row0 + m * 16 + hi4 * 4 + r;
                unsigned short val = f2bf(acc[m][f][r]);
                if (n < 64)       Qo[(size_t)row * HS_ + n]          = val;
                else if (n < 128) Ko[(size_t)row * HS_ + (n - 64)]   = val;
                else              Vto[((size_t)(row >> 8) * 64 + (n - 128)) * 256 + (row & 255)] = val;
            }
        }
    }
}

// ---------- kernel 2: MFMA flash attention, one block per batch ----------
// 512 thr = 8 waves. Wave w owns 16-row q-tiles {w, 15-w} -> 9 kv-steps each.
// Stage K[256][64] + Vt[64][256] in LDS once; main loop has NO block syncs.
#define LDSK 72    // K row stride (elems): 144 B, 16B-aligned, 2-way banks
#define LDSV 264   // Vt row stride: 528 B
#define LDSP 40    // P row stride: 80 B
__global__ __launch_bounds__(512) void attn_mfma(
    const unsigned short* __restrict__ Q,
    const unsigned short* __restrict__ K,
    const unsigned short* __restrict__ Vt,
    float* __restrict__ out)
{
    __shared__ unsigned short Ks[256 * LDSK];      // 36864 B
    __shared__ unsigned short Vts[64 * LDSV];      // 33792 B
    __shared__ unsigned short Ps[8][16 * LDSP];    // 10240 B
    const int t    = threadIdx.x;
    const int w    = t >> 6;
    const int lane = t & 63;
    const int lo   = lane & 15;
    const int hi   = lane >> 4;
    const int b    = blockIdx.x;

    // ---- stage K and Vt ----
    {
        const uint4* gk = (const uint4*)(K + (size_t)b * 256 * HS_);
        #pragma unroll
        for (int i = 0; i < 4; ++i) {
            int idx = t + i * 512;                 // 2048 uint4 = 256 rows x 8
            int r = idx >> 3, c8 = (idx & 7) * 8;
            *(uint4*)&Ks[r * LDSK + c8] = gk[idx];
        }
        const uint4* gv = (const uint4*)(Vt + (size_t)b * 64 * 256);
        #pragma unroll
        for (int i = 0; i < 4; ++i) {
            int idx = t + i * 512;                 // 2048 uint4 = 64 rows x 32
            int r = idx >> 5, c8 = (idx & 31) * 8;
            *(uint4*)&Vts[r * LDSV + c8] = gv[idx];
        }
    }
    __syncthreads();

    unsigned short* Pw = Ps[w];

    auto run_tile = [&](int tq) {
        // Q A-frags (row = lo -> q = tq*16+lo), k = hi*8+j (+32)
        const unsigned short* qp = Q + ((size_t)(b * 256 + tq * 16 + lo)) * HS_ + hi * 8;
        short8 qf0 = *(const short8*)qp;
        short8 qf1 = *(const short8*)(qp + 32);

        f32x4 acc_o[4];
        #pragma unroll
        for (int n = 0; n < 4; ++n) acc_o[n] = (f32x4){0.f, 0.f, 0.f, 0.f};
        float Mr[4] = {-1e30f, -1e30f, -1e30f, -1e30f};
        float Lr[4] = {0.f, 0.f, 0.f, 0.f};

        const int nsteps = (tq >> 1) + 1;
        for (int s = 0; s < nsteps; ++s) {
            const int kv0 = s * 32;
            // QK^T: S[q][kv], q = tq*16 + hi*4 + r, kv = kv0 + n*16 + lo
            f32x4 sa[2];
            sa[0] = (f32x4){0.f, 0.f, 0.f, 0.f};
            sa[1] = (f32x4){0.f, 0.f, 0.f, 0.f};
            #pragma unroll
            for (int n = 0; n < 2; ++n) {
                const unsigned short* kb = &Ks[(kv0 + n * 16 + lo) * LDSK + hi * 8];
                short8 kf0 = *(const short8*)kb;
                short8 kf1 = *(const short8*)(kb + 32);
                sa[n] = __builtin_amdgcn_mfma_f32_16x16x32_bf16(qf0, kf0, sa[n], 0, 0, 0);
                sa[n] = __builtin_amdgcn_mfma_f32_16x16x32_bf16(qf1, kf1, sa[n], 0, 0, 0);
            }
            // causal mask on the final step (kv index > q index -> -inf)
            if (s == nsteps - 1) {
                #pragma unroll
                for (int n = 0; n < 2; ++n)
                    #pragma unroll
                    for (int r = 0; r < 4; ++r) {
                        int kv = kv0 + n * 16 + lo;
                        int q  = tq * 16 + hi * 4 + r;
                        if (kv > q) sa[n][r] = -1e30f;
                    }
            }
            // online softmax per q-row r; reduce over n (in-lane) + 16 col-lanes
            #pragma unroll
            for (int r = 0; r < 4; ++r) {
                float m = fmaxf(sa[0][r], sa[1][r]);
                m = fmaxf(m, __shfl_xor(m, 1));
                m = fmaxf(m, __shfl_xor(m, 2));
                m = fmaxf(m, __shfl_xor(m, 4));
                m = fmaxf(m, __shfl_xor(m, 8));
                float Mn = fmaxf(Mr[r], m);
                float f  = __expf(Mr[r] - Mn);
                Mr[r] = Mn;
                float p0 = __expf(sa[0][r] - Mn);
                float p1 = __expf(sa[1][r] - Mn);
                float ls = p0 + p1;
                ls += __shfl_xor(ls, 1);
                ls += __shfl_xor(ls, 2);
                ls += __shfl_xor(ls, 4);
                ls += __shfl_xor(ls, 8);
                Lr[r] = Lr[r] * f + ls;
                #pragma unroll
                for (int n = 0; n < 4; ++n) acc_o[n][r] *= f;
                Pw[(hi * 4 + r) * LDSP + lo]      = f2bf(p0);
                Pw[(hi * 4 + r) * LDSP + 16 + lo] = f2bf(p1);
            }
            // PV: A = P (row=lo=q', k=hi*8+j=kv'), B = Vt (col=lo=h, k=kv)
            short8 pf = *(const short8*)&Pw[lo * LDSP + hi * 8];
            #pragma unroll
            for (int n = 0; n < 4; ++n) {
                short8 vf = *(const short8*)&Vts[(n * 16 + lo) * LDSV + kv0 + hi * 8];
                acc_o[n] = __builtin_amdgcn_mfma_f32_16x16x32_bf16(pf, vf, acc_o[n], 0, 0, 0);
            }
        }
        // epilogue: out[q][h] = acc_o[n][r]/Lr[r]; h = n*16+lo, q = tq*16+hi*4+r
        #pragma unroll
        for (int r = 0; r < 4; ++r) {
            float inv = 1.0f / Lr[r];
            float* op = out + ((size_t)(b * 256 + tq * 16 + hi * 4 + r)) * HS_ + lo;
            #pragma unroll
            for (int n = 0; n < 4; ++n)
                op[n * 16] = acc_o[n][r] * inv;
        }
    };

    run_tile(w);
    run_tile(15 - w);
}

// ---------- launch ----------
extern "C" void kernel_launch(void* const* d_in, const int* in_sizes, int n_in,
                              void* d_out, int out_size, void* d_ws, size_t ws_size,
                              hipStream_t stream) {
    const float* X  = (const float*)d_in[0];
    const float* Wq = (const float*)d_in[1];
    const float* Wk = (const float*)d_in[2];
    const float* Wv = (const float*)d_in[3];
    float* out = (float*)d_out;

    unsigned short* Q  = (unsigned short*)d_ws;                 // 8 MB
    unsigned short* K  = Q + (size_t)BT_ * HS_;                 // 8 MB
    unsigned short* Vt = K + (size_t)BT_ * HS_;                 // 8 MB (transposed [b*64+h][256])
    unsigned short* Wt = Vt + (size_t)BT_ * HS_;                // 144 KB

    prep_w<<<(192 * C_) / 256, 256, 0, stream>>>(Wq, Wk, Wv, Wt);
    qkv_mfma<<<BT_ / 64, 256, 0, stream>>>(X, Wt, Q, K, Vt);
    attn_mfma<<<B_, 512, 0, stream>>>(Q, K, Vt, out);
}

// Round 4
// 46.889 us; speedup vs baseline: 12.2858x; 1.2698x over previous
//
#include <hip/hip_runtime.h>
#include <hip/hip_bf16.h>

#define B_  256
#define T_  256
#define C_  384
#define HS_ 64
#define BT_ (B_*T_)

typedef __attribute__((ext_vector_type(8))) short short8;
typedef __attribute__((ext_vector_type(4))) float f32x4;

// ---------- helpers ----------
__device__ __forceinline__ unsigned short f2bf(float f) {
    unsigned u = __float_as_uint(f);
    u += 0x7FFFu + ((u >> 16) & 1u);   // round-to-nearest-even
    return (unsigned short)(u >> 16);
}

// ---------- kernel 0: W -> Wt[192][384] bf16 (transposed, Q|K|V stacked) ----------
// Q columns pre-scaled by 384^-0.5 (reference scales scores by C^-0.5).
__global__ __launch_bounds__(256) void prep_w(
    const float* __restrict__ Wq, const float* __restrict__ Wk,
    const float* __restrict__ Wv, unsigned short* __restrict__ Wt)
{
    int i = blockIdx.x * 256 + threadIdx.x;     // 192*384 = 73728 exactly
    int n = i / C_, k = i - n * C_;
    const float* src = (n < 64) ? Wq : (n < 128) ? Wk : Wv;
    float v = src[(size_t)k * HS_ + (n & 63)];
    if (n < 64) v *= 0.05103103630798288f;
    Wt[i] = f2bf(v);
}

// ---------- fused kernel: QKV projection + causal flash attention ----------
// One block per batch. 512 thr = 8 waves. GEMM: M=256 x N=192 x K=384,
// wave (wm,wn) owns rows wm*128..+128, cols wn*48..+48. W frags straight
// from L2 (never staged). Then attention entirely from LDS.
// LDS map (u16 units):
//   Qs  [256][72]  @ 0       (18432)
//   Ks  [256][72]  @ 18432   (18432)
//   Vts [64][264]  @ 36864   (16896)   V transposed: [h][tok]
//   Xs  [2][256][40] @ 53760 (20480)   GEMM staging; aliased by P in attn
// total 74240 u16 = 148480 B
#define LQ_OFF 0
#define LK_OFF 18432
#define LV_OFF 36864
#define LX_OFF 53760
#define LDSP   40

__global__ __launch_bounds__(512, 2) void head_fused(
    const float* __restrict__ X, const unsigned short* __restrict__ Wt,
    float* __restrict__ out)
{
    __shared__ unsigned short lds[74240];
    const int t    = threadIdx.x;
    const int w    = t >> 6;
    const int lane = t & 63;
    const int lo   = lane & 15;
    const int hi   = lane >> 4;
    const int b    = blockIdx.x;
    const int wm   = w >> 2, wn = w & 3;

    const float* Xb = X + (size_t)b * T_ * C_;

    // ================= phase 1: QKV GEMM =================
    const int srow  = t >> 1;       // 0..255
    const int shalf = t & 1;        // which 16-col half of the 32-k chunk

    auto stage_load = [&](int k0, float4* g) {
        const float* p = Xb + (size_t)srow * C_ + k0 + shalf * 16;
        g[0] = *(const float4*)(p);
        g[1] = *(const float4*)(p + 4);
        g[2] = *(const float4*)(p + 8);
        g[3] = *(const float4*)(p + 12);
    };
    auto stage_write = [&](int buf, const float4* g) {
        unsigned short* dst = &lds[LX_OFF + buf * 10240 + srow * 40 + shalf * 16];
        ushort4 p0 = { f2bf(g[0].x), f2bf(g[0].y), f2bf(g[0].z), f2bf(g[0].w) };
        ushort4 p1 = { f2bf(g[1].x), f2bf(g[1].y), f2bf(g[1].z), f2bf(g[1].w) };
        ushort4 p2 = { f2bf(g[2].x), f2bf(g[2].y), f2bf(g[2].z), f2bf(g[2].w) };
        ushort4 p3 = { f2bf(g[3].x), f2bf(g[3].y), f2bf(g[3].z), f2bf(g[3].w) };
        *(ushort4*)(dst)      = p0;
        *(ushort4*)(dst + 4)  = p1;
        *(ushort4*)(dst + 8)  = p2;
        *(ushort4*)(dst + 12) = p3;
    };
    auto load_w = [&](int k0, short8* wf) {    // B-frag: col=wn*48+f*16+lo, k=hi*8+j
        #pragma unroll
        for (int f = 0; f < 3; ++f)
            wf[f] = *(const short8*)(Wt + (size_t)(wn * 48 + f * 16 + lo) * C_ + k0 + hi * 8);
    };

    float4 g[4];
    short8 wf[3];
    stage_load(0, g);
    load_w(0, wf);
    stage_write(0, g);
    __syncthreads();

    f32x4 acc[8][3];
    #pragma unroll
    for (int m = 0; m < 8; ++m)
        #pragma unroll
        for (int f = 0; f < 3; ++f)
            acc[m][f] = (f32x4){0.f, 0.f, 0.f, 0.f};

    #pragma unroll 2
    for (int s = 0; s < 12; ++s) {
        const int cur = s & 1;
        float4 gn[4];
        short8 wfn[3];
        if (s < 11) {                               // issue next-step loads early (T14)
            stage_load((s + 1) * 32, gn);
            load_w((s + 1) * 32, wfn);
        }
        short8 af[8];                               // A-frag: row=lo, k=hi*8+j
        #pragma unroll
        for (int m = 0; m < 8; ++m)
            af[m] = *(const short8*)&lds[LX_OFF + cur * 10240 + (wm * 128 + m * 16 + lo) * 40 + hi * 8];
        #pragma unroll
        for (int m = 0; m < 8; ++m)
            #pragma unroll
            for (int f = 0; f < 3; ++f)
                acc[m][f] = __builtin_amdgcn_mfma_f32_16x16x32_bf16(af[m], wf[f], acc[m][f], 0, 0, 0);
        if (s < 11) {
            stage_write(cur ^ 1, gn);
            wf[0] = wfn[0]; wf[1] = wfn[1]; wf[2] = wfn[2];
        }
        __syncthreads();
    }

    // epilogue: D col = wn*48+f*16+lo, row = wm*128+m*16+hi*4+r  -> LDS Q/K/Vt
    #pragma unroll
    for (int m = 0; m < 8; ++m) {
        const int rowb = wm * 128 + m * 16 + hi * 4;
        #pragma unroll
        for (int f = 0; f < 3; ++f) {
            const int base = wn * 48 + f * 16;      // frag fully inside one of Q/K/V
            if (base < 64) {
                #pragma unroll
                for (int r = 0; r < 4; ++r)
                    lds[LQ_OFF + (rowb + r) * 72 + base + lo] = f2bf(acc[m][f][r]);
            } else if (base < 128) {
                #pragma unroll
                for (int r = 0; r < 4; ++r)
                    lds[LK_OFF + (rowb + r) * 72 + (base - 64) + lo] = f2bf(acc[m][f][r]);
            } else {
                ushort4 pk = { f2bf(acc[m][f][0]), f2bf(acc[m][f][1]),
                               f2bf(acc[m][f][2]), f2bf(acc[m][f][3]) };
                *(ushort4*)&lds[LV_OFF + (base - 128 + lo) * 264 + rowb] = pk;
            }
        }
    }
    __syncthreads();

    // ================= phase 2: causal flash attention =================
    unsigned short* Pw = &lds[LX_OFF + w * 640];    // aliases dead X staging

    auto run_tile = [&](int tq) {
        short8 qf0 = *(const short8*)&lds[LQ_OFF + (tq * 16 + lo) * 72 + hi * 8];
        short8 qf1 = *(const short8*)&lds[LQ_OFF + (tq * 16 + lo) * 72 + hi * 8 + 32];

        f32x4 acc_o[4];
        #pragma unroll
        for (int n = 0; n < 4; ++n) acc_o[n] = (f32x4){0.f, 0.f, 0.f, 0.f};
        float Mr[4] = {-1e30f, -1e30f, -1e30f, -1e30f};
        float Lr[4] = {0.f, 0.f, 0.f, 0.f};

        const int nsteps = (tq >> 1) + 1;
        for (int s = 0; s < nsteps; ++s) {
            const int kv0 = s * 32;
            f32x4 sa[2];
            sa[0] = (f32x4){0.f, 0.f, 0.f, 0.f};
            sa[1] = (f32x4){0.f, 0.f, 0.f, 0.f};
            #pragma unroll
            for (int n = 0; n < 2; ++n) {
                const unsigned short* kb = &lds[LK_OFF + (kv0 + n * 16 + lo) * 72 + hi * 8];
                short8 kf0 = *(const short8*)kb;
                short8 kf1 = *(const short8*)(kb + 32);
                sa[n] = __builtin_amdgcn_mfma_f32_16x16x32_bf16(qf0, kf0, sa[n], 0, 0, 0);
                sa[n] = __builtin_amdgcn_mfma_f32_16x16x32_bf16(qf1, kf1, sa[n], 0, 0, 0);
            }
            if (s == nsteps - 1) {                  // causal mask
                #pragma unroll
                for (int n = 0; n < 2; ++n)
                    #pragma unroll
                    for (int r = 0; r < 4; ++r) {
                        int kv = kv0 + n * 16 + lo;
                        int q  = tq * 16 + hi * 4 + r;
                        if (kv > q) sa[n][r] = -1e30f;
                    }
            }
            #pragma unroll
            for (int r = 0; r < 4; ++r) {
                float m = fmaxf(sa[0][r], sa[1][r]);
                m = fmaxf(m, __shfl_xor(m, 1));
                m = fmaxf(m, __shfl_xor(m, 2));
                m = fmaxf(m, __shfl_xor(m, 4));
                m = fmaxf(m, __shfl_xor(m, 8));
                float Mn = fmaxf(Mr[r], m);
                float fr = __expf(Mr[r] - Mn);
                Mr[r] = Mn;
                float p0 = __expf(sa[0][r] - Mn);
                float p1 = __expf(sa[1][r] - Mn);
                float ls = p0 + p1;
                ls += __shfl_xor(ls, 1);
                ls += __shfl_xor(ls, 2);
                ls += __shfl_xor(ls, 4);
                ls += __shfl_xor(ls, 8);
                Lr[r] = Lr[r] * fr + ls;
                #pragma unroll
                for (int n = 0; n < 4; ++n) acc_o[n][r] *= fr;
                Pw[(hi * 4 + r) * LDSP + lo]      = f2bf(p0);
                Pw[(hi * 4 + r) * LDSP + 16 + lo] = f2bf(p1);
            }
            short8 pf = *(const short8*)&Pw[lo * LDSP + hi * 8];
            #pragma unroll
            for (int n = 0; n < 4; ++n) {
                short8 vf = *(const short8*)&lds[LV_OFF + (n * 16 + lo) * 264 + kv0 + hi * 8];
                acc_o[n] = __builtin_amdgcn_mfma_f32_16x16x32_bf16(pf, vf, acc_o[n], 0, 0, 0);
            }
        }
        #pragma unroll
        for (int r = 0; r < 4; ++r) {
            float inv = 1.0f / Lr[r];
            float* op = out + ((size_t)(b * 256 + tq * 16 + hi * 4 + r)) * HS_ + lo;
            #pragma unroll
            for (int n = 0; n < 4; ++n)
                op[n * 16] = acc_o[n][r] * inv;
        }
    };

    run_tile(w);
    run_tile(15 - w);
}

// ---------- launch ----------
extern "C" void kernel_launch(void* const* d_in, const int* in_sizes, int n_in,
                              void* d_out, int out_size, void* d_ws, size_t ws_size,
                              hipStream_t stream) {
    const float* X  = (const float*)d_in[0];
    const float* Wq = (const float*)d_in[1];
    const float* Wk = (const float*)d_in[2];
    const float* Wv = (const float*)d_in[3];
    float* out = (float*)d_out;

    unsigned short* Wt = (unsigned short*)d_ws;    // 192*384 bf16 = 144 KB

    prep_w<<<(192 * C_) / 256, 256, 0, stream>>>(Wq, Wk, Wv, Wt);
    head_fused<<<B_, 512, 0, stream>>>(X, Wt, out);
}